// Round 11
// baseline (910.750 us; speedup 1.0000x reference)
//
#include <hip/hip_runtime.h>

#define LRC 0.01f
#define LSEQ 4096
#define HIDDIM 128

typedef float f32x2 __attribute__((ext_vector_type(2)));

#define PKFMA(a, b, c) __builtin_elementwise_fma((a), (b), (c))

// x += row_ror(x, N): after {8,4,2,1} every lane holds its 16-lane row's sum.
#define RORADD(x, ctrl)                                                      \
  x += __int_as_float(__builtin_amdgcn_update_dpp(                           \
      0, __float_as_int(x), (ctrl), 0xf, 0xf, true))

__device__ __forceinline__ float rowsum(float x) {
  RORADD(x, 0x128);
  RORADD(x, 0x124);
  RORADD(x, 0x122);
  RORADD(x, 0x121);
  return x;
}

// i-major layout: row-group g = lane>>4 owns inner units {g, 4+g};
// lane (g,t) holds d-block [8t, 8t+8). k/v/b2 replicated across rows.
__global__ __launch_bounds__(64) void ttt_kernel(
    const float* __restrict__ h, const float* __restrict__ W1,
    const float* __restrict__ b1, const float* __restrict__ W2,
    const float* __restrict__ b2, float* __restrict__ out) {
  const int b = blockIdx.x;
  const int lane = threadIdx.x;
  const int g = lane >> 4;         // row-group -> inner units g, 4+g
  const int t8 = (lane & 15) * 8;  // d-block start
  const float* __restrict__ hb = h + (size_t)b * (LSEQ * HIDDIM);

  // ---- weight state ----
  f32x2 w1a[4], w1b[4];  // W1[g][t8+2u..], W1[4+g][..]
  f32x2 w2a[4], w2b[4];  // (W2[d][g], W2[d+1][g]) etc., d = t8+2u
  f32x2 b2l[4];          // b2[t8..t8+8), replicated across rows
#pragma unroll
  for (int u = 0; u < 4; ++u) {
    w1a[u] = *(const f32x2*)(W1 + g * HIDDIM + t8 + 2 * u);
    w1b[u] = *(const f32x2*)(W1 + (4 + g) * HIDDIM + t8 + 2 * u);
    const int dd = t8 + 2 * u;
    w2a[u].x = W2[(size_t)dd * 8 + g];
    w2a[u].y = W2[(size_t)(dd + 1) * 8 + g];
    w2b[u].x = W2[(size_t)dd * 8 + 4 + g];
    w2b[u].y = W2[(size_t)(dd + 1) * 8 + 4 + g];
    b2l[u] = *(const f32x2*)(b2 + dd);
  }
  float b1A = b1[g], b1B = b1[4 + g];
  const float cneg = -(LRC * 2.0f / (float)HIDDIM);
  const f32x2 cnegv = {cneg, cneg};

  auto LOADROW = [&](f32x2* dst, int row) {
    const float* p = hb + (size_t)row * HIDDIM + t8;
    float4 q0 = *(const float4*)p;
    float4 q1 = *(const float4*)(p + 4);
    dst[0] = f32x2{q0.x, q0.y};
    dst[1] = f32x2{q0.z, q0.w};
    dst[2] = f32x2{q1.x, q1.y};
    dst[3] = f32x2{q1.z, q1.w};
  };

  // ---- 3-slot k/v rotation ----
  f32x2 kA[4], vA[4], kB[4], vB[4], kC[4], vC[4];
  LOADROW(kA, 0); LOADROW(vA, 1);
  LOADROW(kB, 2); LOADROW(vB, 3);
  LOADROW(kC, 4); LOADROW(vC, 5);

  // ---- a(0) = W1 k(0) + b1 (row-mapped scalars) ----
  float aA, aB;
  {
    f32x2 ta = w1a[0] * kA[0], tb = w1b[0] * kA[0];
#pragma unroll
    for (int u = 1; u < 4; ++u) {
      ta = PKFMA(w1a[u], kA[u], ta);
      tb = PKFMA(w1b[u], kA[u], tb);
    }
    aA = rowsum(ta.x + ta.y) + b1A;
    aB = rowsum(tb.x + tb.y) + b1B;
  }

  // One SGD step. Rank-1 factorization (validated R6):
  //   a(s+1) = red(W1(s)k(s+1)) + da(s)*(red(k(s)·k(s+1)) + 1) + b1(s)
  auto STEP = [&](const f32x2* k, const f32x2* v, const f32x2* kn) {
    float rA = fmaxf(aA, 0.0f), rB = fmaxf(aB, 0.0f);
    f32x2 rrA = {rA, rA}, rrB = {rB, rB};
    // pred partial: this row's two inner-unit contributions
    f32x2 p[4];
#pragma unroll
    for (int u = 0; u < 4; ++u) p[u] = PKFMA(w2b[u], rrB, w2a[u] * rrA);
    // independent: tp/kk partials with OLD W1 (fills shfl shadows)
    f32x2 ta = w1a[0] * kn[0], tb = w1b[0] * kn[0], kc = k[0] * kn[0];
#pragma unroll
    for (int u = 1; u < 4; ++u) {
      ta = PKFMA(w1a[u], kn[u], ta);
      tb = PKFMA(w1b[u], kn[u], tb);
      kc = PKFMA(k[u], kn[u], kc);
    }
    float tpA = ta.x + ta.y, tpB = tb.x + tb.y, kkp = kc.x + kc.y;
    // cross-row sum of pred: lanes ^16 then ^32 (t preserved)
#pragma unroll
    for (int u = 0; u < 4; ++u) {
      p[u].x += __shfl_xor(p[u].x, 16, 64);
      p[u].y += __shfl_xor(p[u].y, 16, 64);
    }
    // row reductions for tp/kk in the shuffle shadow
    tpA = rowsum(tpA);
    tpB = rowsum(tpB);
    kkp = rowsum(kkp);
#pragma unroll
    for (int u = 0; u < 4; ++u) {
      p[u].x += __shfl_xor(p[u].x, 32, 64);
      p[u].y += __shfl_xor(p[u].y, 32, 64);
    }
    // gl = cneg * (pred + b2 - v), identical across rows
    f32x2 gl[4];
#pragma unroll
    for (int u = 0; u < 4; ++u) gl[u] = ((p[u] + b2l[u]) - v[u]) * cnegv;
    // dp partials on OLD w2 -> row reductions -> mask (all lane-local)
    f32x2 da_ = w2a[0] * gl[0], db_ = w2b[0] * gl[0];
#pragma unroll
    for (int u = 1; u < 4; ++u) {
      da_ = PKFMA(w2a[u], gl[u], da_);
      db_ = PKFMA(w2b[u], gl[u], db_);
    }
    float dpA = rowsum(da_.x + da_.y);
    float dpB = rowsum(db_.x + db_.y);
    float daA = (aA > 0.0f) ? dpA : 0.0f;  // == -lr * da_ref
    float daB = (aB > 0.0f) ? dpB : 0.0f;
    // updates: W1 += da k^T, W2 += gl r^T, b2 += gl (no cross-lane needed)
    f32x2 ddA = {daA, daA}, ddB = {daB, daB};
#pragma unroll
    for (int u = 0; u < 4; ++u) {
      w1a[u] = PKFMA(ddA, k[u], w1a[u]);
      w1b[u] = PKFMA(ddB, k[u], w1b[u]);
      w2a[u] = PKFMA(gl[u], rrA, w2a[u]);
      w2b[u] = PKFMA(gl[u], rrB, w2b[u]);
      b2l[u] = b2l[u] + gl[u];
    }
    float kkp1 = kkp + 1.0f;
    aA = fmaf(daA, kkp1, tpA + b1A);
    aB = fmaf(daB, kkp1, tpB + b1B);
    b1A += daA;
    b1B += daB;
  };

  // steps 0..2042: 681 iterations x 3 (3-slot rotation, R6 schedule)
  f32x2 kc[4], vc[4];
  for (int it = 0; it < 681; ++it) {
    {
#pragma unroll
      for (int u = 0; u < 4; ++u) { kc[u] = kA[u]; vc[u] = vA[u]; }
      LOADROW(kA, 6 * it + 6);
      LOADROW(vA, 6 * it + 7);
      STEP(kc, vc, kB);  // s = 3it
    }
    {
#pragma unroll
      for (int u = 0; u < 4; ++u) { kc[u] = kB[u]; vc[u] = vB[u]; }
      LOADROW(kB, 6 * it + 8);
      LOADROW(vB, 6 * it + 9);
      STEP(kc, vc, kC);  // s = 3it+1
    }
    {
#pragma unroll
      for (int u = 0; u < 4; ++u) { kc[u] = kC[u]; vc[u] = vC[u]; }
      LOADROW(kC, 6 * it + 10);
      LOADROW(vC, 6 * it + 11);
      STEP(kc, vc, kA);  // s = 3it+2, kn = freshly loaded k(3it+3)
    }
  }

  // tail: steps 2043..2046, then final predict with row 4095
  f32x2 kD[4], vD[4], kE[4], xv[4];
  LOADROW(kD, 4092);
  LOADROW(vD, 4093);
  LOADROW(kE, 4094);
  LOADROW(xv, 4095);
  STEP(kA, vA, kB);  // 2043
  STEP(kB, vB, kC);  // 2044
  STEP(kC, vC, kD);  // 2045
  STEP(kD, vD, kE);  // 2046 (kn only feeds a discarded a)

  // ---- final prediction with x = h[b, L-1] ----
  {
    f32x2 ta = w1a[0] * xv[0], tb = w1b[0] * xv[0];
#pragma unroll
    for (int u = 1; u < 4; ++u) {
      ta = PKFMA(w1a[u], xv[u], ta);
      tb = PKFMA(w1b[u], xv[u], tb);
    }
    float fA = rowsum(ta.x + ta.y) + b1A;
    float fB = rowsum(tb.x + tb.y) + b1B;
    float rA = fmaxf(fA, 0.0f), rB = fmaxf(fB, 0.0f);
    f32x2 rrA = {rA, rA}, rrB = {rB, rB};
    f32x2 p[4];
#pragma unroll
    for (int u = 0; u < 4; ++u) p[u] = PKFMA(w2b[u], rrB, w2a[u] * rrA);
#pragma unroll
    for (int u = 0; u < 4; ++u) {
      p[u].x += __shfl_xor(p[u].x, 16, 64);
      p[u].y += __shfl_xor(p[u].y, 16, 64);
    }
#pragma unroll
    for (int u = 0; u < 4; ++u) {
      p[u].x += __shfl_xor(p[u].x, 32, 64);
      p[u].y += __shfl_xor(p[u].y, 32, 64);
    }
    if (g == 0) {
      f32x2 o0 = p[0] + b2l[0], o1 = p[1] + b2l[1];
      f32x2 o2 = p[2] + b2l[2], o3 = p[3] + b2l[3];
      float4 s0 = {o0.x, o0.y, o1.x, o1.y};
      float4 s1 = {o2.x, o2.y, o3.x, o3.y};
      float* op = out + (size_t)b * HIDDIM + t8;
      *(float4*)op = s0;
      *(float4*)(op + 4) = s1;
    }
  }
}

extern "C" void kernel_launch(void* const* d_in, const int* in_sizes, int n_in,
                              void* d_out, int out_size, void* d_ws, size_t ws_size,
                              hipStream_t stream) {
  const float* h  = (const float*)d_in[0];
  const float* W1 = (const float*)d_in[1];
  const float* b1 = (const float*)d_in[2];
  const float* W2 = (const float*)d_in[3];
  const float* b2 = (const float*)d_in[4];
  float* out = (float*)d_out;
  ttt_kernel<<<256, 64, 0, stream>>>(h, W1, b1, W2, b2, out);
}

// Round 12
// 761.058 us; speedup vs baseline: 1.1967x; 1.1967x over previous
//
#include <hip/hip_runtime.h>

#define LRC 0.01f
#define LSEQ 4096
#define HIDDIM 128

typedef float f32x2 __attribute__((ext_vector_type(2)));
typedef unsigned int u32x2 __attribute__((ext_vector_type(2)));

#define PKFMA(a, b, c) __builtin_elementwise_fma((a), (b), (c))

// x += row_ror(x, N): after {8,4,2,1} every lane holds its 16-lane row's sum.
#define RORADD(x, ctrl)                                                      \
  x += __int_as_float(__builtin_amdgcn_update_dpp(                           \
      0, __float_as_int(x), (ctrl), 0xf, 0xf, true))

__device__ __forceinline__ float rowsum(float x) {
  RORADD(x, 0x128);
  RORADD(x, 0x124);
  RORADD(x, 0x122);
  RORADD(x, 0x121);
  return x;
}

// Cross-row folds on the VALU pipe (self-swap pattern validated in R5/R6):
// xrow16: lanes get (row0+row1) / (row2+row3) sums within each 32-half;
// xrow32: lanes get the sum across the two 32-halves.
__device__ __forceinline__ float xrow16(float x) {
  u32x2 s = __builtin_amdgcn_permlane16_swap(__float_as_uint(x),
                                             __float_as_uint(x), false, false);
  return __uint_as_float(s.x) + __uint_as_float(s.y);
}
__device__ __forceinline__ float xrow32(float x) {
  u32x2 s = __builtin_amdgcn_permlane32_swap(__float_as_uint(x),
                                             __float_as_uint(x), false, false);
  return __uint_as_float(s.x) + __uint_as_float(s.y);
}

// i-major layout: row-group g = lane>>4 owns inner units {g, 4+g};
// lane (g,t) holds d-block [8t, 8t+8). k/v/b2 replicated across rows.
__global__ __launch_bounds__(64) void ttt_kernel(
    const float* __restrict__ h, const float* __restrict__ W1,
    const float* __restrict__ b1, const float* __restrict__ W2,
    const float* __restrict__ b2, float* __restrict__ out) {
  const int b = blockIdx.x;
  const int lane = threadIdx.x;
  const int g = lane >> 4;         // row-group -> inner units g, 4+g
  const int t8 = (lane & 15) * 8;  // d-block start
  const float* __restrict__ hb = h + (size_t)b * (LSEQ * HIDDIM);

  // ---- weight state ----
  f32x2 w1a[4], w1b[4];  // W1[g][t8+2u..], W1[4+g][..]
  f32x2 w2a[4], w2b[4];  // (W2[d][g], W2[d+1][g]) etc., d = t8+2u
  f32x2 b2l[4];          // b2[t8..t8+8), replicated across rows
#pragma unroll
  for (int u = 0; u < 4; ++u) {
    w1a[u] = *(const f32x2*)(W1 + g * HIDDIM + t8 + 2 * u);
    w1b[u] = *(const f32x2*)(W1 + (4 + g) * HIDDIM + t8 + 2 * u);
    const int dd = t8 + 2 * u;
    w2a[u].x = W2[(size_t)dd * 8 + g];
    w2a[u].y = W2[(size_t)(dd + 1) * 8 + g];
    w2b[u].x = W2[(size_t)dd * 8 + 4 + g];
    w2b[u].y = W2[(size_t)(dd + 1) * 8 + 4 + g];
    b2l[u] = *(const f32x2*)(b2 + dd);
  }
  float b1A = b1[g], b1B = b1[4 + g];
  const float cneg = -(LRC * 2.0f / (float)HIDDIM);
  const f32x2 cnegv = {cneg, cneg};

  auto LOADROW = [&](f32x2* dst, const float* rowp) {
    const float* p = rowp + t8;
    float4 q0 = *(const float4*)p;
    float4 q1 = *(const float4*)(p + 4);
    dst[0] = f32x2{q0.x, q0.y};
    dst[1] = f32x2{q0.z, q0.w};
    dst[2] = f32x2{q1.x, q1.y};
    dst[3] = f32x2{q1.z, q1.w};
  };

  // ---- 4-slot k/v rotation: slot X holds step (4it + X) ----
  f32x2 kA[4], vA[4], kB[4], vB[4], kC[4], vC[4], kD[4], vD[4];
  LOADROW(kA, hb + 0 * HIDDIM);
  LOADROW(vA, hb + 1 * HIDDIM);
  LOADROW(kB, hb + 2 * HIDDIM);
  LOADROW(vB, hb + 3 * HIDDIM);
  LOADROW(kC, hb + 4 * HIDDIM);
  LOADROW(vC, hb + 5 * HIDDIM);
  LOADROW(kD, hb + 6 * HIDDIM);
  LOADROW(vD, hb + 7 * HIDDIM);

  // ---- a(0) = W1 k(0) + b1 (row-mapped scalars) ----
  float aA, aB;
  {
    f32x2 ta = w1a[0] * kA[0], tb = w1b[0] * kA[0];
#pragma unroll
    for (int u = 1; u < 4; ++u) {
      ta = PKFMA(w1a[u], kA[u], ta);
      tb = PKFMA(w1b[u], kA[u], tb);
    }
    aA = rowsum(ta.x + ta.y) + b1A;
    aB = rowsum(tb.x + tb.y) + b1B;
  }

  // One SGD step. Rank-1 factorization (validated R6/R10):
  //   a(s+1) = red(W1(s)k(s+1)) + da(s)*(red(k(s)·k(s+1)) + 1) + b1(s)
  auto STEP = [&](const f32x2* k, const f32x2* v, const f32x2* kn) {
    float rA = fmaxf(aA, 0.0f), rB = fmaxf(aB, 0.0f);
    f32x2 rrA = {rA, rA}, rrB = {rB, rB};
    // pred partial: this row's two inner-unit contributions
    float ps[8];
#pragma unroll
    for (int u = 0; u < 4; ++u) {
      f32x2 p = PKFMA(w2b[u], rrB, w2a[u] * rrA);
      ps[2 * u] = p.x;
      ps[2 * u + 1] = p.y;
    }
    // cross-row stage 1 (VALU permlane folds, 8 independent chains)
#pragma unroll
    for (int e = 0; e < 8; ++e) ps[e] = xrow16(ps[e]);
    // independent tp/kk partials with OLD W1 fill the shadow
    f32x2 ta = w1a[0] * kn[0], tb = w1b[0] * kn[0], kc = k[0] * kn[0];
#pragma unroll
    for (int u = 1; u < 4; ++u) {
      ta = PKFMA(w1a[u], kn[u], ta);
      tb = PKFMA(w1b[u], kn[u], tb);
      kc = PKFMA(k[u], kn[u], kc);
    }
    float tpA = ta.x + ta.y, tpB = tb.x + tb.y, kkp = kc.x + kc.y;
    // cross-row stage 2
#pragma unroll
    for (int e = 0; e < 8; ++e) ps[e] = xrow32(ps[e]);
    // row reductions for tp/kk (3 braided DPP chains)
    tpA = rowsum(tpA);
    tpB = rowsum(tpB);
    kkp = rowsum(kkp);
    // gl = cneg * (pred + b2 - v), identical across rows
    f32x2 gl[4];
#pragma unroll
    for (int u = 0; u < 4; ++u) {
      f32x2 pp = {ps[2 * u], ps[2 * u + 1]};
      gl[u] = ((pp + b2l[u]) - v[u]) * cnegv;
    }
    // dp partials on OLD w2 -> row reductions -> mask (lane-local)
    f32x2 da_ = w2a[0] * gl[0], db_ = w2b[0] * gl[0];
#pragma unroll
    for (int u = 1; u < 4; ++u) {
      da_ = PKFMA(w2a[u], gl[u], da_);
      db_ = PKFMA(w2b[u], gl[u], db_);
    }
    float dpA = rowsum(da_.x + da_.y);
    float dpB = rowsum(db_.x + db_.y);
    float daA = (aA > 0.0f) ? dpA : 0.0f;  // == -lr * da_ref
    float daB = (aB > 0.0f) ? dpB : 0.0f;
    // updates: W1 += da k^T, W2 += gl r^T, b2 += gl (no cross-lane)
    f32x2 ddA = {daA, daA}, ddB = {daB, daB};
#pragma unroll
    for (int u = 0; u < 4; ++u) {
      w1a[u] = PKFMA(ddA, k[u], w1a[u]);
      w1b[u] = PKFMA(ddB, k[u], w1b[u]);
      w2a[u] = PKFMA(gl[u], rrA, w2a[u]);
      w2b[u] = PKFMA(gl[u], rrB, w2b[u]);
      b2l[u] = b2l[u] + gl[u];
    }
    float kkp1 = kkp + 1.0f;
    aA = fmaf(daA, kkp1, tpA + b1A);
    aB = fmaf(daB, kkp1, tpB + b1B);
    b1A += daA;
    b1B += daB;
  };

  // steps 0..2043: 511 iterations x 4 legs; loads issued AFTER each STEP
  // (slot consumed -> immediately refilled for step s+4, ~3-step distance)
  const float* pf = hb;  // row 8*it
  for (int it = 0; it < 511; ++it) {
    const float* pn = pf + 8 * HIDDIM;
    STEP(kA, vA, kB);              // s = 4it
    LOADROW(kA, pn + 0 * HIDDIM);  // k(4it+4) = row 8it+8
    LOADROW(vA, pn + 1 * HIDDIM);
    STEP(kB, vB, kC);              // s = 4it+1
    LOADROW(kB, pn + 2 * HIDDIM);
    LOADROW(vB, pn + 3 * HIDDIM);
    STEP(kC, vC, kD);              // s = 4it+2
    LOADROW(kC, pn + 4 * HIDDIM);
    LOADROW(vC, pn + 5 * HIDDIM);
    STEP(kD, vD, kA);              // s = 4it+3, kn = freshly loaded k(4it+4)
    LOADROW(kD, pn + 6 * HIDDIM);
    LOADROW(vD, pn + 7 * HIDDIM);
    pf = pn;
  }
  // after loop: slots hold steps 2044..2047 (rows 4088..4095)
  STEP(kA, vA, kB);  // 2044
  STEP(kB, vB, kC);  // 2045
  STEP(kC, vC, kD);  // 2046 (kn = k(2047) = row 4094; extra a discarded)

  // ---- final prediction with x = h[b, L-1] = vD (row 4095) ----
  {
    const f32x2* xv = vD;
    f32x2 ta = w1a[0] * xv[0], tb = w1b[0] * xv[0];
#pragma unroll
    for (int u = 1; u < 4; ++u) {
      ta = PKFMA(w1a[u], xv[u], ta);
      tb = PKFMA(w1b[u], xv[u], tb);
    }
    float fA = rowsum(ta.x + ta.y) + b1A;
    float fB = rowsum(tb.x + tb.y) + b1B;
    float rA = fmaxf(fA, 0.0f), rB = fmaxf(fB, 0.0f);
    f32x2 rrA = {rA, rA}, rrB = {rB, rB};
    float ps[8];
#pragma unroll
    for (int u = 0; u < 4; ++u) {
      f32x2 p = PKFMA(w2b[u], rrB, w2a[u] * rrA);
      ps[2 * u] = p.x;
      ps[2 * u + 1] = p.y;
    }
#pragma unroll
    for (int e = 0; e < 8; ++e) ps[e] = xrow16(ps[e]);
#pragma unroll
    for (int e = 0; e < 8; ++e) ps[e] = xrow32(ps[e]);
    if (g == 0) {
      float4 s0 = {ps[0] + b2l[0].x, ps[1] + b2l[0].y,
                   ps[2] + b2l[1].x, ps[3] + b2l[1].y};
      float4 s1 = {ps[4] + b2l[2].x, ps[5] + b2l[2].y,
                   ps[6] + b2l[3].x, ps[7] + b2l[3].y};
      float* op = out + (size_t)b * HIDDIM + t8;
      *(float4*)op = s0;
      *(float4*)(op + 4) = s1;
    }
  }
}

extern "C" void kernel_launch(void* const* d_in, const int* in_sizes, int n_in,
                              void* d_out, int out_size, void* d_ws, size_t ws_size,
                              hipStream_t stream) {
  const float* h  = (const float*)d_in[0];
  const float* W1 = (const float*)d_in[1];
  const float* b1 = (const float*)d_in[2];
  const float* W2 = (const float*)d_in[3];
  const float* b2 = (const float*)d_in[4];
  float* out = (float*)d_out;
  ttt_kernel<<<256, 64, 0, stream>>>(h, W1, b1, W2, b2, out);
}

// Round 13
// 742.295 us; speedup vs baseline: 1.2269x; 1.0253x over previous
//
#include <hip/hip_runtime.h>

#define LRC 0.01f
#define LSEQ 4096
#define HIDDIM 128

typedef float f32x2 __attribute__((ext_vector_type(2)));
typedef unsigned int u32x2 __attribute__((ext_vector_type(2)));

#define RL(x, L) __int_as_float(__builtin_amdgcn_readlane(__float_as_int(x), (L)))
#define RORADD(x, ctrl)                                                      \
  x += __int_as_float(__builtin_amdgcn_update_dpp(                           \
      0, __float_as_int(x), (ctrl), 0xf, 0xf, true))

// (validated R5/R6) 4 concurrent 64-lane sums, row-mapped outputs:
// row g (lanes 16g..16g+15) holds sum of x_{sig(g)}, sig = [0,2,1,3].
__device__ __forceinline__ float allred4(float x0, float x1, float x2,
                                         float x3) {
  u32x2 s1 = __builtin_amdgcn_permlane32_swap(__float_as_uint(x0),
                                              __float_as_uint(x1), false, false);
  float z01 = __uint_as_float(s1.x) + __uint_as_float(s1.y);
  u32x2 s2 = __builtin_amdgcn_permlane32_swap(__float_as_uint(x2),
                                              __float_as_uint(x3), false, false);
  float z23 = __uint_as_float(s2.x) + __uint_as_float(s2.y);
  u32x2 s3 = __builtin_amdgcn_permlane16_swap(__float_as_uint(z01),
                                              __float_as_uint(z23), false, false);
  float y = __uint_as_float(s3.x) + __uint_as_float(s3.y);
  RORADD(y, 0x128); RORADD(y, 0x124); RORADD(y, 0x122); RORADD(y, 0x121);
  return y;
}

// (validated R6) 64-lane sum, all-lane-uniform result.
__device__ __forceinline__ float allred1(float x) {
  u32x2 s1 = __builtin_amdgcn_permlane32_swap(__float_as_uint(x),
                                              __float_as_uint(x), false, false);
  float z = __uint_as_float(s1.x) + __uint_as_float(s1.y);
  u32x2 s2 = __builtin_amdgcn_permlane16_swap(__float_as_uint(z),
                                              __float_as_uint(z), false, false);
  z = __uint_as_float(s2.x) + __uint_as_float(s2.y);
  RORADD(z, 0x128); RORADD(z, 0x124); RORADD(z, 0x122); RORADD(z, 0x121);
  return z;
}

// Barrier WITHOUT vmcnt drain: global prefetches stay in flight across steps;
// lgkmcnt(0) makes this wave's LDS writes visible at the barrier.
#define BAR() asm volatile("s_waitcnt lgkmcnt(0)\n\ts_barrier" ::: "memory")

// LDS float layout: initT [0..8) | TP slot p: [8+8p..) x4 | kk slot p: [40+2p) x4
//                   | da slot p: [48+8p..) x4   (total 80 floats)
//
// Wave A (serial core) step j: reads TP/kk slot (j+1)&3 (1 barrier old),
//   computes da(j) -> writes da slot j&3, forms a(j+1) via
//   a(j+1) = TP(j+1) + da(j-1)*kk(j-1,j+1) + da(j)*kk(j,j+1) + b1(j+1).
// Wave B (W1 owner) step j: reads da(j-1) slot (j-1)&3 (1 barrier old),
//   W1 += da(j-1) x k(j-1), writes TP(j+2)=W1*k(j+2), kk(j,j+2), kk(j+1,j+2)
//   into slot (j+2)&3.
__global__ __launch_bounds__(128) void ttt_kernel(
    const float* __restrict__ h, const float* __restrict__ W1,
    const float* __restrict__ b1, const float* __restrict__ W2,
    const float* __restrict__ b2, float* __restrict__ out) {
  __shared__ __align__(16) float sm[80];
  const int b = blockIdx.x;
  const int tid = threadIdx.x;
  const int wv = tid >> 6;
  const int lane = tid & 63;
  const int g = lane >> 4;
  const int sig = ((g & 1) << 1) | (g >> 1);  // row g holds inner unit sig(g)
  const int d0 = lane * 2;                    // lane owns dims d0, d0+1
  const float* __restrict__ hb = h + (size_t)b * (LSEQ * HIDDIM);

  if (wv == 0) {
    // ======================= WAVE A =======================
    const float cneg = -(LRC * 2.0f / (float)HIDDIM);
    f32x2 w2v[8];
#pragma unroll
    for (int i = 0; i < 8; ++i) {
      w2v[i].x = W2[(size_t)d0 * 8 + i];
      w2v[i].y = W2[(size_t)(d0 + 1) * 8 + i];
    }
    f32x2 b2v = *(const f32x2*)(b2 + d0);
    float b1A = b1[sig], b1B = b1[4 + sig];
    // v(s) = row 2s+1 ; 4-slot rotation, 4-step prefetch distance
    f32x2 v0 = *(const f32x2*)(hb + 1 * HIDDIM + d0);
    f32x2 v1 = *(const f32x2*)(hb + 3 * HIDDIM + d0);
    f32x2 v2 = *(const f32x2*)(hb + 5 * HIDDIM + d0);
    f32x2 v3 = *(const f32x2*)(hb + 7 * HIDDIM + d0);
    float daPA = 0.0f, daPB = 0.0f;

    BAR();  // init barrier: B's initT / TP(1) / kk(1) ready

    float aA = sm[sig] + b1A;      // a(0), row-mapped
    float aB = sm[4 + sig] + b1B;

    auto STEPA = [&](int rd, int wr, f32x2& vS, const float* vld) {
      // LDS reads (written >=1 barrier ago)
      float tA = sm[8 + 8 * rd + sig];
      float tB = sm[8 + 8 * rd + 4 + sig];
      float kk1 = sm[40 + 2 * rd];
      float kk2 = sm[40 + 2 * rd + 1];
      f32x2 vcur = vS;
      if (vld) vS = *(const f32x2*)(vld + d0);  // refill freed slot (4 ahead)
      float rA = fmaxf(aA, 0.0f), rB = fmaxf(aB, 0.0f);
      float r0 = RL(rA, 0), r1 = RL(rA, 32), r2 = RL(rA, 16), r3 = RL(rA, 48);
      float r4 = RL(rB, 0), r5 = RL(rB, 32), r6 = RL(rB, 16), r7 = RL(rB, 48);
      // pred = W2 r + b2 (two partial chains)
      float px0 = fmaf(w2v[0].x, r0, b2v.x), py0 = fmaf(w2v[0].y, r0, b2v.y);
      float px1 = w2v[1].x * r1, py1 = w2v[1].y * r1;
      px0 = fmaf(w2v[2].x, r2, px0); py0 = fmaf(w2v[2].y, r2, py0);
      px1 = fmaf(w2v[3].x, r3, px1); py1 = fmaf(w2v[3].y, r3, py1);
      px0 = fmaf(w2v[4].x, r4, px0); py0 = fmaf(w2v[4].y, r4, py0);
      px1 = fmaf(w2v[5].x, r5, px1); py1 = fmaf(w2v[5].y, r5, py1);
      px0 = fmaf(w2v[6].x, r6, px0); py0 = fmaf(w2v[6].y, r6, py0);
      px1 = fmaf(w2v[7].x, r7, px1); py1 = fmaf(w2v[7].y, r7, py1);
      float glx = (px0 + px1 - vcur.x) * cneg;
      float gly = (py0 + py1 - vcur.y) * cneg;
      // dp partials on OLD w2 -> row-mapped reductions -> mask
      float dp[8];
#pragma unroll
      for (int i = 0; i < 8; ++i) dp[i] = fmaf(w2v[i].x, glx, w2v[i].y * gly);
      float zA = allred4(dp[0], dp[1], dp[2], dp[3]);
      float zB = allred4(dp[4], dp[5], dp[6], dp[7]);
      float daA = (aA > 0.0f) ? zA : 0.0f;  // == -lr * da_ref
      float daB = (aB > 0.0f) ? zB : 0.0f;
      if ((lane & 15) == 0) {  // rowlead handoff: daS[i] = da_i
        sm[48 + 8 * wr + sig] = daA;
        sm[48 + 8 * wr + 4 + sig] = daB;
      }
      // W2 / b2 update (off critical path)
      w2v[0].x = fmaf(glx, r0, w2v[0].x); w2v[0].y = fmaf(gly, r0, w2v[0].y);
      w2v[1].x = fmaf(glx, r1, w2v[1].x); w2v[1].y = fmaf(gly, r1, w2v[1].y);
      w2v[2].x = fmaf(glx, r2, w2v[2].x); w2v[2].y = fmaf(gly, r2, w2v[2].y);
      w2v[3].x = fmaf(glx, r3, w2v[3].x); w2v[3].y = fmaf(gly, r3, w2v[3].y);
      w2v[4].x = fmaf(glx, r4, w2v[4].x); w2v[4].y = fmaf(gly, r4, w2v[4].y);
      w2v[5].x = fmaf(glx, r5, w2v[5].x); w2v[5].y = fmaf(gly, r5, w2v[5].y);
      w2v[6].x = fmaf(glx, r6, w2v[6].x); w2v[6].y = fmaf(gly, r6, w2v[6].y);
      w2v[7].x = fmaf(glx, r7, w2v[7].x); w2v[7].y = fmaf(gly, r7, w2v[7].y);
      b2v.x += glx;
      b2v.y += gly;
      // a(j+1) = TP + daPrev*kk1 + daCur*kk2 + b1(j+1)
      b1A += daA;
      b1B += daB;
      aA = fmaf(daPA, kk1, fmaf(daA, kk2, tA + b1A));
      aB = fmaf(daPB, kk1, fmaf(daB, kk2, tB + b1B));
      daPA = daA;
      daPB = daB;
      BAR();
    };

    // steps 0..2043 (511 x 4), slots static per leg
    for (int it = 0; it < 511; ++it) {
      const float* base = hb + (size_t)(8 * it) * HIDDIM;
      STEPA(1, 0, v0, base + 9 * HIDDIM);   // j=4it   : v(4it+4) = row 8it+9
      STEPA(2, 1, v1, base + 11 * HIDDIM);  // j=4it+1
      STEPA(3, 2, v2, base + 13 * HIDDIM);  // j=4it+2
      STEPA(0, 3, v3, base + 15 * HIDDIM);  // j=4it+3
    }
    STEPA(1, 0, v0, (const float*)nullptr);  // j=2044
    STEPA(2, 1, v1, (const float*)nullptr);  // j=2045
    STEPA(3, 2, v2, (const float*)nullptr);  // j=2046
    // epilogue: aA/aB hold a(2047) = W1(final) x + b1(final)
    {
      float rA = fmaxf(aA, 0.0f), rB = fmaxf(aB, 0.0f);
      float r0 = RL(rA, 0), r1 = RL(rA, 32), r2 = RL(rA, 16), r3 = RL(rA, 48);
      float r4 = RL(rB, 0), r5 = RL(rB, 32), r6 = RL(rB, 16), r7 = RL(rB, 48);
      float ox = fmaf(w2v[0].x, r0, b2v.x), oy = fmaf(w2v[0].y, r0, b2v.y);
      ox = fmaf(w2v[1].x, r1, ox); oy = fmaf(w2v[1].y, r1, oy);
      ox = fmaf(w2v[2].x, r2, ox); oy = fmaf(w2v[2].y, r2, oy);
      ox = fmaf(w2v[3].x, r3, ox); oy = fmaf(w2v[3].y, r3, oy);
      ox = fmaf(w2v[4].x, r4, ox); oy = fmaf(w2v[4].y, r4, oy);
      ox = fmaf(w2v[5].x, r5, ox); oy = fmaf(w2v[5].y, r5, oy);
      ox = fmaf(w2v[6].x, r6, ox); oy = fmaf(w2v[6].y, r6, oy);
      ox = fmaf(w2v[7].x, r7, ox); oy = fmaf(w2v[7].y, r7, oy);
      f32x2 o = {ox, oy};
      *(f32x2*)(out + (size_t)b * HIDDIM + d0) = o;
    }
  } else {
    // ======================= WAVE B =======================
    f32x2 w1v[8];
#pragma unroll
    for (int i = 0; i < 8; ++i)
      w1v[i] = *(const f32x2*)(W1 + i * HIDDIM + d0);
    // k(m) = row 2m (m<=2046), k(2047) = row 4095 (the final x)
    f32x2 k0 = *(const f32x2*)(hb + 0 * HIDDIM + d0);
    f32x2 k1 = *(const f32x2*)(hb + 2 * HIDDIM + d0);
    f32x2 k2 = *(const f32x2*)(hb + 4 * HIDDIM + d0);
    f32x2 k3 = *(const f32x2*)(hb + 6 * HIDDIM + d0);
    f32x2 kPrev = k0;  // k(j-1); j=0 value irrelevant (da(-1)=0)
    // zero da slots (read by B at j=0 before A wrote anything)
    if (lane < 32) sm[48 + lane] = 0.0f;
    // initT = red(W1init k(0)); TP(1) = red(W1init k(1)); kk slot1 = {0, k0.k1}
    {
      float pa[8], pb[8];
#pragma unroll
      for (int i = 0; i < 8; ++i) {
        pa[i] = fmaf(w1v[i].x, k0.x, w1v[i].y * k0.y);
        pb[i] = fmaf(w1v[i].x, k1.x, w1v[i].y * k1.y);
      }
      float iA = allred4(pa[0], pa[1], pa[2], pa[3]);
      float iB = allred4(pa[4], pa[5], pa[6], pa[7]);
      float tA = allred4(pb[0], pb[1], pb[2], pb[3]);
      float tB = allred4(pb[4], pb[5], pb[6], pb[7]);
      float kk01 = allred1(fmaf(k0.x, k1.x, k0.y * k1.y));
      if ((lane & 15) == 0) {
        sm[sig] = iA;
        sm[4 + sig] = iB;
        sm[8 + 8 * 1 + sig] = tA;
        sm[8 + 8 * 1 + 4 + sig] = tB;
      }
      if (lane == 0) {
        sm[40 + 2 * 1] = 0.0f;   // kk(-1,1): multiplied by daPrev=0
        sm[40 + 2 * 1 + 1] = kk01;
      }
    }
    BAR();  // init barrier

    auto STEPB = [&](int daRd, int wr, f32x2& s0, f32x2& s1, f32x2& s2,
                     const float* kld) {
      // read da(j-1), uniform (written 1 barrier ago)
      float4 q0 = *(float4*)&sm[48 + 8 * daRd];
      float4 q1 = *(float4*)&sm[48 + 8 * daRd + 4];
      float da[8] = {q0.x, q0.y, q0.z, q0.w, q1.x, q1.y, q1.z, q1.w};
#pragma unroll
      for (int i = 0; i < 8; ++i) {
        w1v[i].x = fmaf(da[i], kPrev.x, w1v[i].x);
        w1v[i].y = fmaf(da[i], kPrev.y, w1v[i].y);
      }
      // TP(j+2) = red(W1[j] k(j+2)); kk(j,j+2), kk(j+1,j+2)
      float tp[8];
#pragma unroll
      for (int i = 0; i < 8; ++i) tp[i] = fmaf(w1v[i].x, s2.x, w1v[i].y * s2.y);
      float kkp1 = fmaf(s0.x, s2.x, s0.y * s2.y);
      float kkp2 = fmaf(s1.x, s2.x, s1.y * s2.y);
      float tA = allred4(tp[0], tp[1], tp[2], tp[3]);
      float tB = allred4(tp[4], tp[5], tp[6], tp[7]);
      float u1 = allred1(kkp1);
      float u2 = allred1(kkp2);
      if ((lane & 15) == 0) {
        sm[8 + 8 * wr + sig] = tA;
        sm[8 + 8 * wr + 4 + sig] = tB;
      }
      if (lane == 0) {
        sm[40 + 2 * wr] = u1;
        sm[40 + 2 * wr + 1] = u2;
      }
      kPrev = s0;
      if (kld) s0 = *(const f32x2*)(kld + d0);  // k(j+4)
      BAR();
    };

    // steps j = 0..2043 (511 x 4)
    for (int it = 0; it < 511; ++it) {
      const float* base = hb + (size_t)(8 * it) * HIDDIM;
      // leg3's load is k(4it+7): row 8it+14, except m=2047 -> row 4095
      const float* l3 = (it == 510) ? (hb + (size_t)4095 * HIDDIM)
                                    : (base + 14 * HIDDIM);
      STEPB(3, 2, k0, k1, k2, base + 8 * HIDDIM);   // j=4it
      STEPB(0, 3, k1, k2, k3, base + 10 * HIDDIM);  // j=4it+1
      STEPB(1, 0, k2, k3, k0, base + 12 * HIDDIM);  // j=4it+2
      STEPB(2, 1, k3, k0, k1, l3);                  // j=4it+3
    }
    STEPB(3, 2, k0, k1, k2, (const float*)nullptr);  // j=2044
    STEPB(0, 3, k1, k2, k3, (const float*)nullptr);  // j=2045 (s2 = x)
    BAR();  // pad to match A's barrier count (A: 2048, B: 2046+1+this = 2048)
  }
}

extern "C" void kernel_launch(void* const* d_in, const int* in_sizes, int n_in,
                              void* d_out, int out_size, void* d_ws, size_t ws_size,
                              hipStream_t stream) {
  const float* h  = (const float*)d_in[0];
  const float* W1 = (const float*)d_in[1];
  const float* b1 = (const float*)d_in[2];
  const float* W2 = (const float*)d_in[3];
  const float* b2 = (const float*)d_in[4];
  float* out = (float*)d_out;
  ttt_kernel<<<256, 128, 0, stream>>>(h, W1, b1, W2, b2, out);
}

// Round 14
// 533.105 us; speedup vs baseline: 1.7084x; 1.3924x over previous
//
#include <hip/hip_runtime.h>

#define LRC 0.01f
#define LSEQ 4096
#define HIDDIM 128

typedef float f32x2 __attribute__((ext_vector_type(2)));
typedef unsigned int u32x2 __attribute__((ext_vector_type(2)));

#define RL(x, L) __int_as_float(__builtin_amdgcn_readlane(__float_as_int(x), (L)))
#define RORADD(x, ctrl)                                                      \
  x += __int_as_float(__builtin_amdgcn_update_dpp(                           \
      0, __float_as_int(x), (ctrl), 0xf, 0xf, true))

// (validated R5/R6/R12) 4 concurrent 64-lane sums, row-mapped outputs:
// row g holds sum of x_{sig(g)}, sig = [0,2,1,3]. Rowlead write at
// sm[base+sig] lands value c at sm[base+c].
__device__ __forceinline__ float allred4(float x0, float x1, float x2,
                                         float x3) {
  u32x2 s1 = __builtin_amdgcn_permlane32_swap(__float_as_uint(x0),
                                              __float_as_uint(x1), false, false);
  float z01 = __uint_as_float(s1.x) + __uint_as_float(s1.y);
  u32x2 s2 = __builtin_amdgcn_permlane32_swap(__float_as_uint(x2),
                                              __float_as_uint(x3), false, false);
  float z23 = __uint_as_float(s2.x) + __uint_as_float(s2.y);
  u32x2 s3 = __builtin_amdgcn_permlane16_swap(__float_as_uint(z01),
                                              __float_as_uint(z23), false, false);
  float y = __uint_as_float(s3.x) + __uint_as_float(s3.y);
  RORADD(y, 0x128); RORADD(y, 0x124); RORADD(y, 0x122); RORADD(y, 0x121);
  return y;
}

// (validated R6) 64-lane sum, all-lane-uniform result.
__device__ __forceinline__ float allred1(float x) {
  u32x2 s1 = __builtin_amdgcn_permlane32_swap(__float_as_uint(x),
                                              __float_as_uint(x), false, false);
  float z = __uint_as_float(s1.x) + __uint_as_float(s1.y);
  u32x2 s2 = __builtin_amdgcn_permlane16_swap(__float_as_uint(z),
                                              __float_as_uint(z), false, false);
  z = __uint_as_float(s2.x) + __uint_as_float(s2.y);
  RORADD(z, 0x128); RORADD(z, 0x124); RORADD(z, 0x122); RORADD(z, 0x121);
  return z;
}

// Barrier WITHOUT vmcnt drain: global prefetches stay in flight.
#define BAR() asm volatile("s_waitcnt lgkmcnt(0)\n\ts_barrier" ::: "memory")

// LDS floats: TP[ep][2][8] at ep*16 | KK[ep][5] at 32+ep*5 | DA[ep][2][8] at
// 48+ep*16. Epoch e (steps P=2e, Q=2e+1): A reads TP/KK[e&1] (B wrote in
// e-1), writes DA[e&1]; B reads DA[1-(e&1)] (A wrote in e-1), writes
// TP/KK[1-(e&1)] for epoch e+1. One barrier per epoch.
//
// Factorization: a(P) = TPb(P) + da(2e-2)kk1 + da(2e-1)kk2 + b1, with
// TPb(P) = red(W[2e-3] k(P)); a(Q) adds da(P)kk5. B's kk set (epoch e-1,
// k-window k(2e-2..2e+1)): kk1=k(2e-2)k(2e), kk2=k(2e-1)k(2e),
// kk3=k(2e-2)k(2e+1), kk4=k(2e-1)k(2e+1), kk5=k(2e)k(2e+1).
__global__ __launch_bounds__(128) void ttt_kernel(
    const float* __restrict__ h, const float* __restrict__ W1,
    const float* __restrict__ b1, const float* __restrict__ W2,
    const float* __restrict__ b2, float* __restrict__ out) {
  __shared__ __align__(16) float sm[80];
  const int b = blockIdx.x;
  const int tid = threadIdx.x;
  const int wv = tid >> 6;
  const int lane = tid & 63;
  const int g = lane >> 4;
  const int sig = ((g & 1) << 1) | (g >> 1);
  const int d0 = lane * 2;
  const float* __restrict__ hb = h + (size_t)b * (LSEQ * HIDDIM);

  if (wv == 0) {
    // ======================= WAVE A (serial core) =======================
    const float cneg = -(LRC * 2.0f / (float)HIDDIM);
    f32x2 w2v[8];
#pragma unroll
    for (int i = 0; i < 8; ++i) {
      w2v[i].x = W2[(size_t)d0 * 8 + i];
      w2v[i].y = W2[(size_t)(d0 + 1) * 8 + i];
    }
    f32x2 b2v = *(const f32x2*)(b2 + d0);
    float b1A = b1[sig], b1B = b1[4 + sig];
    // v(j) = row 2j+1; 4 live slots + 2 incoming
    f32x2 vS0 = *(const f32x2*)(hb + 1 * HIDDIM + d0);
    f32x2 vS1 = *(const f32x2*)(hb + 3 * HIDDIM + d0);
    f32x2 vS2 = *(const f32x2*)(hb + 5 * HIDDIM + d0);
    f32x2 vS3 = *(const f32x2*)(hb + 7 * HIDDIM + d0);
    float pGlx = 0.0f, pGly = 0.0f;  // deferred Q-step W2/b2 update
    float pR0 = 0, pR1 = 0, pR2 = 0, pR3 = 0, pR4 = 0, pR5 = 0, pR6 = 0,
          pR7 = 0;
    float dm2A = 0, dm2B = 0, dm1A = 0, dm1B = 0;  // da(j-2), da(j-1)

    BAR();  // init: B's a0-base / TP(1) / KK ready

    // serial core for one step; defer=true stashes the W2/b2 update
    auto CORE = [&](float aA, float aB, f32x2 vcur, float& daAo, float& daBo,
                    bool defer) {
      float rA = fmaxf(aA, 0.0f), rB = fmaxf(aB, 0.0f);
      float r0 = RL(rA, 0), r1 = RL(rA, 32), r2 = RL(rA, 16), r3 = RL(rA, 48);
      float r4 = RL(rB, 0), r5 = RL(rB, 32), r6 = RL(rB, 16), r7 = RL(rB, 48);
      float px0 = fmaf(w2v[0].x, r0, b2v.x), py0 = fmaf(w2v[0].y, r0, b2v.y);
      float px1 = w2v[1].x * r1, py1 = w2v[1].y * r1;
      px0 = fmaf(w2v[2].x, r2, px0); py0 = fmaf(w2v[2].y, r2, py0);
      px1 = fmaf(w2v[3].x, r3, px1); py1 = fmaf(w2v[3].y, r3, py1);
      px0 = fmaf(w2v[4].x, r4, px0); py0 = fmaf(w2v[4].y, r4, py0);
      px1 = fmaf(w2v[5].x, r5, px1); py1 = fmaf(w2v[5].y, r5, py1);
      px0 = fmaf(w2v[6].x, r6, px0); py0 = fmaf(w2v[6].y, r6, py0);
      px1 = fmaf(w2v[7].x, r7, px1); py1 = fmaf(w2v[7].y, r7, py1);
      float glx = (px0 + px1 - vcur.x) * cneg;
      float gly = (py0 + py1 - vcur.y) * cneg;
      float dp[8];
#pragma unroll
      for (int i = 0; i < 8; ++i) dp[i] = fmaf(w2v[i].x, glx, w2v[i].y * gly);
      float zA = allred4(dp[0], dp[1], dp[2], dp[3]);
      float zB = allred4(dp[4], dp[5], dp[6], dp[7]);
      daAo = (aA > 0.0f) ? zA : 0.0f;
      daBo = (aB > 0.0f) ? zB : 0.0f;
      if (!defer) {
        w2v[0].x = fmaf(glx, r0, w2v[0].x); w2v[0].y = fmaf(gly, r0, w2v[0].y);
        w2v[1].x = fmaf(glx, r1, w2v[1].x); w2v[1].y = fmaf(gly, r1, w2v[1].y);
        w2v[2].x = fmaf(glx, r2, w2v[2].x); w2v[2].y = fmaf(gly, r2, w2v[2].y);
        w2v[3].x = fmaf(glx, r3, w2v[3].x); w2v[3].y = fmaf(gly, r3, w2v[3].y);
        w2v[4].x = fmaf(glx, r4, w2v[4].x); w2v[4].y = fmaf(gly, r4, w2v[4].y);
        w2v[5].x = fmaf(glx, r5, w2v[5].x); w2v[5].y = fmaf(gly, r5, w2v[5].y);
        w2v[6].x = fmaf(glx, r6, w2v[6].x); w2v[6].y = fmaf(gly, r6, w2v[6].y);
        w2v[7].x = fmaf(glx, r7, w2v[7].x); w2v[7].y = fmaf(gly, r7, w2v[7].y);
        b2v.x += glx;
        b2v.y += gly;
      } else {
        pGlx = glx; pGly = gly;
        pR0 = r0; pR1 = r1; pR2 = r2; pR3 = r3;
        pR4 = r4; pR5 = r5; pR6 = r6; pR7 = r7;
      }
    };

    auto APPLY_PEND = [&]() {
      w2v[0].x = fmaf(pGlx, pR0, w2v[0].x); w2v[0].y = fmaf(pGly, pR0, w2v[0].y);
      w2v[1].x = fmaf(pGlx, pR1, w2v[1].x); w2v[1].y = fmaf(pGly, pR1, w2v[1].y);
      w2v[2].x = fmaf(pGlx, pR2, w2v[2].x); w2v[2].y = fmaf(pGly, pR2, w2v[2].y);
      w2v[3].x = fmaf(pGlx, pR3, w2v[3].x); w2v[3].y = fmaf(pGly, pR3, w2v[3].y);
      w2v[4].x = fmaf(pGlx, pR4, w2v[4].x); w2v[4].y = fmaf(pGly, pR4, w2v[4].y);
      w2v[5].x = fmaf(pGlx, pR5, w2v[5].x); w2v[5].y = fmaf(pGly, pR5, w2v[5].y);
      w2v[6].x = fmaf(pGlx, pR6, w2v[6].x); w2v[6].y = fmaf(pGly, pR6, w2v[6].y);
      w2v[7].x = fmaf(pGlx, pR7, w2v[7].x); w2v[7].y = fmaf(pGly, pR7, w2v[7].y);
      b2v.x += pGlx;
      b2v.y += pGly;
    };

    auto EPA = [&](int ep, int e) {
      const int tpo = ep * 16, kko = 32 + ep * 5, dao = 48 + ep * 16;
      int rv0 = 4 * e + 9;  if (rv0 > 4095) rv0 = 4095;
      int rv1 = 4 * e + 11; if (rv1 > 4095) rv1 = 4095;
      f32x2 vI0 = *(const f32x2*)(hb + (size_t)rv0 * HIDDIM + d0);
      f32x2 vI1 = *(const f32x2*)(hb + (size_t)rv1 * HIDDIM + d0);
      float tpPA = sm[tpo + sig], tpPB = sm[tpo + 4 + sig];
      float tpQA = sm[tpo + 8 + sig], tpQB = sm[tpo + 12 + sig];
      float kk1 = sm[kko], kk2 = sm[kko + 1], kk3 = sm[kko + 2],
            kk4 = sm[kko + 3], kk5 = sm[kko + 4];
      APPLY_PEND();  // prev epoch's Q update; shadows the LDS reads
      float aA = fmaf(dm2A, kk1, fmaf(dm1A, kk2, tpPA + b1A));
      float aB = fmaf(dm2B, kk1, fmaf(dm1B, kk2, tpPB + b1B));
      float daPA, daPB;
      CORE(aA, aB, vS0, daPA, daPB, false);
      if ((lane & 15) == 0) { sm[dao + sig] = daPA; sm[dao + 4 + sig] = daPB; }
      b1A += daPA;
      b1B += daPB;
      float aQA = fmaf(dm2A, kk3, fmaf(dm1A, kk4, fmaf(daPA, kk5, tpQA + b1A)));
      float aQB = fmaf(dm2B, kk3, fmaf(dm1B, kk4, fmaf(daPB, kk5, tpQB + b1B)));
      float daQA, daQB;
      CORE(aQA, aQB, vS1, daQA, daQB, true);
      if ((lane & 15) == 0) { sm[dao + 8 + sig] = daQA; sm[dao + 12 + sig] = daQB; }
      b1A += daQA;
      b1B += daQB;
      dm2A = daPA; dm2B = daPB;
      dm1A = daQA; dm1B = daQB;
      vS0 = vS2; vS1 = vS3; vS2 = vI0; vS3 = vI1;
      BAR();
    };

    for (int pr = 0; pr < 511; ++pr) {
      EPA(0, 2 * pr);
      EPA(1, 2 * pr + 1);
    }
    EPA(0, 1022);
    // tail: epoch 1023 = step 2046 + final predict (buffer ep=1)
    {
      float tpPA = sm[16 + sig], tpPB = sm[20 + sig];
      float tpQA = sm[24 + sig], tpQB = sm[28 + sig];
      float kk1 = sm[37], kk2 = sm[38], kk3 = sm[39], kk4 = sm[40],
            kk5 = sm[41];
      APPLY_PEND();
      float aA = fmaf(dm2A, kk1, fmaf(dm1A, kk2, tpPA + b1A));
      float aB = fmaf(dm2B, kk1, fmaf(dm1B, kk2, tpPB + b1B));
      float daA, daB;
      CORE(aA, aB, vS0, daA, daB, false);  // step 2046, W2/b2 inline
      b1A += daA;
      b1B += daB;
      // a(2047) = red(W[2046] x) + b1  (x = row 4095, fed in as k(2047))
      float fA = fmaf(dm2A, kk3, fmaf(dm1A, kk4, fmaf(daA, kk5, tpQA + b1A)));
      float fB = fmaf(dm2B, kk3, fmaf(dm1B, kk4, fmaf(daB, kk5, tpQB + b1B)));
      float rA = fmaxf(fA, 0.0f), rB = fmaxf(fB, 0.0f);
      float r0 = RL(rA, 0), r1 = RL(rA, 32), r2 = RL(rA, 16), r3 = RL(rA, 48);
      float r4 = RL(rB, 0), r5 = RL(rB, 32), r6 = RL(rB, 16), r7 = RL(rB, 48);
      float ox = fmaf(w2v[0].x, r0, b2v.x), oy = fmaf(w2v[0].y, r0, b2v.y);
      ox = fmaf(w2v[1].x, r1, ox); oy = fmaf(w2v[1].y, r1, oy);
      ox = fmaf(w2v[2].x, r2, ox); oy = fmaf(w2v[2].y, r2, oy);
      ox = fmaf(w2v[3].x, r3, ox); oy = fmaf(w2v[3].y, r3, oy);
      ox = fmaf(w2v[4].x, r4, ox); oy = fmaf(w2v[4].y, r4, oy);
      ox = fmaf(w2v[5].x, r5, ox); oy = fmaf(w2v[5].y, r5, oy);
      ox = fmaf(w2v[6].x, r6, ox); oy = fmaf(w2v[6].y, r6, oy);
      ox = fmaf(w2v[7].x, r7, ox); oy = fmaf(w2v[7].y, r7, oy);
      f32x2 o = {ox, oy};
      *(f32x2*)(out + (size_t)b * HIDDIM + d0) = o;
    }
  } else {
    // ======================= WAVE B (W1 owner) =======================
    f32x2 w1v[8];
#pragma unroll
    for (int i = 0; i < 8; ++i)
      w1v[i] = *(const f32x2*)(W1 + i * HIDDIM + d0);
    // k(m) = row 2m (m<2047); k(2047) := x = row 4095
    f32x2 kR2 = *(const f32x2*)(hb + 0 * HIDDIM + d0);   // k(0)
    f32x2 kR3 = *(const f32x2*)(hb + 2 * HIDDIM + d0);   // k(1)
    f32x2 kR4 = *(const f32x2*)(hb + 4 * HIDDIM + d0);   // k(2)
    f32x2 kR5 = *(const f32x2*)(hb + 6 * HIDDIM + d0);   // k(3)
    f32x2 kR0 = kR2, kR1 = kR2;                          // dummies (da=0)
    f32x2 kI0 = *(const f32x2*)(hb + 8 * HIDDIM + d0);   // k(4)
    f32x2 kI1 = *(const f32x2*)(hb + 10 * HIDDIM + d0);  // k(5)
    if (lane < 16) sm[64 + lane] = 0.0f;  // zero DA[1] (read at epoch 0)
    {
      float pa[8], pb[8];
#pragma unroll
      for (int i = 0; i < 8; ++i) {
        pa[i] = fmaf(w1v[i].x, kR2.x, w1v[i].y * kR2.y);
        pb[i] = fmaf(w1v[i].x, kR3.x, w1v[i].y * kR3.y);
      }
      float zA = allred4(pa[0], pa[1], pa[2], pa[3]);
      float zB = allred4(pa[4], pa[5], pa[6], pa[7]);
      float tA = allred4(pb[0], pb[1], pb[2], pb[3]);
      float tB = allred4(pb[4], pb[5], pb[6], pb[7]);
      float kk01 = allred1(fmaf(kR2.x, kR3.x, kR2.y * kR3.y));
      if ((lane & 15) == 0) {
        sm[0 + sig] = zA;   sm[4 + sig] = zB;    // a(0) base
        sm[8 + sig] = tA;   sm[12 + sig] = tB;   // TP(1)
      }
      if (lane < 4) sm[32 + lane] = 0.0f;        // kk1..kk4 = 0 (x da=0)
      if (lane == 0) sm[36] = kk01;              // kk5 = k(0)·k(1)
    }
    BAR();  // init

    auto EPB = [&](int ep, int e) {
      const int dao = 48 + (1 - ep) * 16;
      const int tpo = (1 - ep) * 16, kko = 32 + (1 - ep) * 5;
      int m6 = 2 * e + 6, m7 = 2 * e + 7;
      int r6 = (m6 >= 2047) ? 4095 : 2 * m6;
      int r7 = (m7 >= 2047) ? 4095 : 2 * m7;
      f32x2 kN0 = *(const f32x2*)(hb + (size_t)r6 * HIDDIM + d0);
      f32x2 kN1 = *(const f32x2*)(hb + (size_t)r7 * HIDDIM + d0);
      float4 qa = *(float4*)&sm[dao], qb = *(float4*)&sm[dao + 4];
      float4 qc = *(float4*)&sm[dao + 8], qd = *(float4*)&sm[dao + 12];
      // kk partials (k-only) fill the da-read shadow
      float c1 = fmaf(kR2.x, kR4.x, kR2.y * kR4.y);
      float c2 = fmaf(kR3.x, kR4.x, kR3.y * kR4.y);
      float c3 = fmaf(kR2.x, kR5.x, kR2.y * kR5.y);
      float c4 = fmaf(kR3.x, kR5.x, kR3.y * kR5.y);
      float c5 = fmaf(kR4.x, kR5.x, kR4.y * kR5.y);
      float ykk = allred4(c1, c2, c3, c4);
      float yk5 = allred1(c5);
      float daP[8] = {qa.x, qa.y, qa.z, qa.w, qb.x, qb.y, qb.z, qb.w};
      float daQ[8] = {qc.x, qc.y, qc.z, qc.w, qd.x, qd.y, qd.z, qd.w};
#pragma unroll
      for (int i = 0; i < 8; ++i) {
        w1v[i].x = fmaf(daP[i], kR0.x, w1v[i].x);
        w1v[i].y = fmaf(daP[i], kR0.y, w1v[i].y);
      }
#pragma unroll
      for (int i = 0; i < 8; ++i) {
        w1v[i].x = fmaf(daQ[i], kR1.x, w1v[i].x);
        w1v[i].y = fmaf(daQ[i], kR1.y, w1v[i].y);
      }
      float tp[8], tq[8];
#pragma unroll
      for (int i = 0; i < 8; ++i) {
        tp[i] = fmaf(w1v[i].x, kR4.x, w1v[i].y * kR4.y);
        tq[i] = fmaf(w1v[i].x, kR5.x, w1v[i].y * kR5.y);
      }
      float tA = allred4(tp[0], tp[1], tp[2], tp[3]);
      float tB = allred4(tp[4], tp[5], tp[6], tp[7]);
      float uA = allred4(tq[0], tq[1], tq[2], tq[3]);
      float uB = allred4(tq[4], tq[5], tq[6], tq[7]);
      if ((lane & 15) == 0) {
        sm[tpo + sig] = tA;      sm[tpo + 4 + sig] = tB;
        sm[tpo + 8 + sig] = uA;  sm[tpo + 12 + sig] = uB;
        sm[kko + sig] = ykk;
      }
      if (lane == 0) sm[kko + 4] = yk5;
      kR0 = kR2; kR1 = kR3; kR2 = kR4; kR3 = kR5;
      kR4 = kI0; kR5 = kI1; kI0 = kN0; kI1 = kN1;
      BAR();
    };

    for (int pr = 0; pr < 511; ++pr) {
      EPB(0, 2 * pr);
      EPB(1, 2 * pr + 1);
    }
    EPB(0, 1022);
  }
}

extern "C" void kernel_launch(void* const* d_in, const int* in_sizes, int n_in,
                              void* d_out, int out_size, void* d_ws, size_t ws_size,
                              hipStream_t stream) {
  const float* h  = (const float*)d_in[0];
  const float* W1 = (const float*)d_in[1];
  const float* b1 = (const float*)d_in[2];
  const float* W2 = (const float*)d_in[3];
  const float* b2 = (const float*)d_in[4];
  float* out = (float*)d_out;
  ttt_kernel<<<256, 128, 0, stream>>>(h, W1, b1, W2, b2, out);
}